// Round 4
// baseline (331.142 us; speedup 1.0000x reference)
//
#include <hip/hip_runtime.h>

typedef __bf16 bf16x8 __attribute__((ext_vector_type(8)));
typedef __bf16 bf16x4 __attribute__((ext_vector_type(4)));
typedef float f32x16 __attribute__((ext_vector_type(16)));

__device__ __forceinline__ unsigned short f2bf(float f) {
    union { float f; unsigned u; } v; v.f = f;
    unsigned r = (v.u + 0x7FFFu + ((v.u >> 16) & 1u)) >> 16;
    return (unsigned short)r;
}

// pinned async global load: volatile asm keeps issue order vs the volatile waitcnts
#define GLD(dst, ptr) asm volatile("global_load_dwordx4 %0, %1, off" : "=v"(dst) : "v"(ptr))
// counted wait + scheduling fence (rule #18: stops MFMAs hoisting above the wait)
#define VMWAIT(N) do { asm volatile("s_waitcnt vmcnt(" #N ")" ::: "memory"); \
                       __builtin_amdgcn_sched_barrier(0); } while (0)

// ---- weight conversion into MFMA fragment order (32x32x16 bf16) ----
// Frag mapping: lane l holds W[k0 + (l>>5)*8 + j][n0 + (l&31)], j=0..7.
// W1F index = ((g*8 + kb)*64 + l)*8 + j   (g: hidden col-group 0..31, kb: K-step 0..7, K pad 119->128)
// W2F index = ((gn*64 + kb)*64 + l)*8 + j (gn: out col-group 0..7, kb: K-step 0..63)
__global__ void conv_w(const float* __restrict__ W1, const float* __restrict__ W2,
                       unsigned short* __restrict__ W1F, unsigned short* __restrict__ W2F) {
    int b = blockIdx.x;
    if (b < 512) {
        int idx = b * 256 + threadIdx.x;                   // 131072
        int j = idx & 7, l = (idx >> 3) & 63, kb = (idx >> 9) & 7, g = idx >> 12;
        int k = kb * 16 + (l >> 5) * 8 + j;
        int h = g * 32 + (l & 31);
        float v = (k < 119) ? W1[(size_t)k * 1024 + h] : 0.0f;
        W1F[idx] = f2bf(v);
    } else {
        int idx = (b - 512) * 256 + threadIdx.x;           // 262144
        int j = idx & 7, l = (idx >> 3) & 63, kb = (idx >> 9) & 63, gn = idx >> 15;
        int k = kb * 16 + (l >> 5) * 8 + j;
        int n = gn * 32 + (l & 31);
        W2F[idx] = f2bf(W2[(size_t)k * 256 + n]);
    }
}

// ---- fused features + MLP ----
// 256 threads (4 waves), 64 rows/block, grid 2048. chunk = 128 hidden cols (8 chunks).
// All weight/bias loads are asm-pinned global_load_dwordx4 with counted s_waitcnt vmcnt(N):
// wf2(c+1) stays in flight across the barrier; wf1(c+1) latency hides under phase B MFMAs.
// Volatile-asm ordering pins the issue points; sched_barrier(0) after each wait pins the uses.
__global__ __launch_bounds__(256, 2) void mlp_fused(
    const float* __restrict__ hole, const float* __restrict__ board,
    const float* __restrict__ b1, const float* __restrict__ b2,
    const unsigned short* __restrict__ W1F, const unsigned short* __restrict__ W2F,
    float* __restrict__ out)
{
    __shared__ unsigned short Xs[64 * 128];       // 16 KB, swizzled
    __shared__ unsigned short Hs[2][64 * 128];    // 2 x 16 KB, swizzled

    const int tid  = threadIdx.x;
    const int w    = tid >> 6;
    const int lane = tid & 63;
    const int l32  = lane & 31;
    const int hi   = lane >> 5;      // 0/1 half-wave
    const long r0  = (long)blockIdx.x * 64;

    // ---------------- feature extraction: thread t < 64 handles row r0+t ----------------
    if (tid < 64) {
        const long r = r0 + tid;
        const float4* hp = (const float4*)(hole + r * 52);
        const float4* bp = (const float4*)(board + r * 52);
        unsigned long long hm = 0ull, bm = 0ull;
        #pragma unroll
        for (int i = 0; i < 13; ++i) {
            float4 h4 = hp[i], b4 = bp[i];
            int base = i * 4;
            hm |= ((unsigned long long)(h4.x > 0.5f)) << (base + 0);
            hm |= ((unsigned long long)(h4.y > 0.5f)) << (base + 1);
            hm |= ((unsigned long long)(h4.z > 0.5f)) << (base + 2);
            hm |= ((unsigned long long)(h4.w > 0.5f)) << (base + 3);
            bm |= ((unsigned long long)(b4.x > 0.5f)) << (base + 0);
            bm |= ((unsigned long long)(b4.y > 0.5f)) << (base + 1);
            bm |= ((unsigned long long)(b4.z > 0.5f)) << (base + 2);
            bm |= ((unsigned long long)(b4.w > 0.5f)) << (base + 3);
        }
        const unsigned long long am = hm | bm;
        const int bcount = __popcll(bm);
        const int hcount = __popcll(hm);

        int pairs_b = 0, pairs_a = 0;
        bool trips_b = false, trips_a = false;
        unsigned prb = 0, pra = 0;
        #pragma unroll
        for (int rr = 0; rr < 13; ++rr) {
            int cb = __popc((unsigned)((bm >> (4 * rr)) & 0xFull));
            int ca = __popc((unsigned)((am >> (4 * rr)) & 0xFull));
            pairs_b += (cb >= 2); trips_b = trips_b || (cb >= 3); prb |= (unsigned)(cb > 0) << rr;
            pairs_a += (ca >= 2); trips_a = trips_a || (ca >= 3); pra |= (unsigned)(ca > 0) << rr;
        }
        const unsigned long long SM = 0x1111111111111ull;
        int bscm = 0, ascm = 0;
        #pragma unroll
        for (int s = 0; s < 4; ++s) {
            int bs = __popcll(bm & (SM << s));
            int as = __popcll(am & (SM << s));
            bscm = bs > bscm ? bs : bscm;
            ascm = as > ascm ? as : ascm;
        }
        float strength = trips_b ? 0.8f : (pairs_b >= 2 ? 0.6f : (pairs_b >= 1 ? 0.4f : 0.2f));
        if (bcount == 0) strength = 0.0f;
        float flush_b = (bscm >= 3 && bcount > 0) ? 1.0f : 0.0f;
        bool sb = false;
        #pragma unroll
        for (int i = 0; i < 13; ++i) sb = sb || (__popc((prb >> i) & 0x1Fu) >= 3);
        float straight_b = (sb && bcount > 0) ? 1.0f : 0.0f;
        float gr0 = (bcount == 0) ? 1.0f : 0.0f;
        float gr3 = (bcount == 3) ? 1.0f : 0.0f;
        float gr4 = (bcount == 4) ? 1.0f : 0.0f;
        float gr5 = (bcount == 5) ? 1.0f : 0.0f;
        float valid = (hcount >= 2 && bcount >= 1) ? 1.0f : 0.0f;
        float flush_draw = (ascm == 4) ? 1.0f : 0.0f;
        float flush_outs = fmaxf(0.0f, 13.0f - (float)ascm) * (1.0f / 13.0f);
        int first = -1;
        #pragma unroll
        for (int i = 0; i < 13; ++i) {
            bool qq = (((pra >> i) & 1u) != 0u) && (__popc((pra >> i) & 0x1Fu) >= 4);
            if (qq && first < 0) first = i;
        }
        float straight_draw = (first >= 0) ? 1.0f : 0.0f;
        float straight_outs = 0.0f;
        if (first >= 0) {
            int c4 = __popc((pra >> first) & 0xFu);
            straight_outs = (c4 >= 4) ? 0.4f : 0.2f;
        }
        float total_outs = flush_draw * flush_outs * 9.0f + straight_draw * straight_outs * 8.0f;
        float remaining = 52.0f - (float)(hcount + bcount);
        float equity = 0.0f;
        if (remaining > 0.0f) equity = fminf(1.0f, total_outs / fmaxf(remaining, 1.0f));
        float hit_pair  = (pairs_a >= 1) ? 1.0f : 0.0f;
        float hit_trips = trips_a ? 1.0f : 0.0f;
        float hit_two   = (pairs_a >= 2) ? 1.0f : 0.0f;

        unsigned short* xrow = &Xs[tid * 128];
        const int fsw = (tid & 7) << 3;          // swizzle constant for this row
        #pragma unroll
        for (int i = 0; i < 52; ++i) xrow[i ^ fsw]        = ((hm >> i) & 1ull) ? (unsigned short)0x3F80 : (unsigned short)0;
        #pragma unroll
        for (int i = 0; i < 52; ++i) xrow[(52 + i) ^ fsw] = ((bm >> i) & 1ull) ? (unsigned short)0x3F80 : (unsigned short)0;
        float feats[15] = { strength, flush_b, straight_b, gr0, gr3, gr4, gr5,
                            valid * flush_draw, valid * flush_outs, valid * straight_draw,
                            valid * straight_outs, valid * equity,
                            valid * hit_pair, valid * hit_trips, valid * hit_two };
        #pragma unroll
        for (int i = 0; i < 15; ++i) xrow[(104 + i) ^ fsw] = f2bf(feats[i]);
        #pragma unroll
        for (int i = 119; i < 128; ++i) xrow[i ^ fsw] = 0;
    }

    f32x16 acc[2][2];
    #pragma unroll
    for (int a = 0; a < 2; ++a)
        #pragma unroll
        for (int b = 0; b < 2; ++b)
            #pragma unroll
            for (int r = 0; r < 16; ++r) acc[a][b][r] = 0.0f;

    __syncthreads();   // Xs visible; drains vmcnt to 0 -> counted sequence starts clean

    const int sw = (l32 & 7) << 3;               // rows l32 and 32+l32 share (r&7)
    unsigned short* const x0 = &Xs[l32 * 128];
    unsigned short* const x1 = &Xs[(32 + l32) * 128];

    f32x16 h0, h1;
    float4 wf1r[8];      // W1F frags for the chunk being phase-A'd (asm-loaded)
    float4 bqr[4];       // bias quads (asm-loaded)
    float4 wf2r[16];     // W2F frags for next phase B: [0..7]=n-group 2w, [8..15]=2w+1

    // ---- prologue: issue wf1(0)+bias(0) (12), then wf2(0) (16); wait for the first 12 ----
    {
        const unsigned short* w1p = W1F + ((size_t)(0 * 4 + w) * 8) * 512 + lane * 8;
        #pragma unroll
        for (int ks = 0; ks < 8; ++ks) GLD(wf1r[ks], (const void*)(w1p + ks * 512));
        #pragma unroll
        for (int q = 0; q < 4; ++q) GLD(bqr[q], (const void*)&b1[0 * 128 + w * 32 + 8 * q + 4 * hi]);
        const unsigned short* w2p0 = W2F + ((size_t)(2 * w + 0) * 64 + 0 * 8) * 512 + lane * 8;
        const unsigned short* w2p1 = W2F + ((size_t)(2 * w + 1) * 64 + 0 * 8) * 512 + lane * 8;
        #pragma unroll
        for (int ks = 0; ks < 8; ++ks) {
            GLD(wf2r[ks],     (const void*)(w2p0 + ks * 512));
            GLD(wf2r[8 + ks], (const void*)(w2p1 + ks * 512));
        }
        VMWAIT(16);   // only the 16 wf2 loads still outstanding -> wf1(0)+bias(0) ready

        // ---- phase A, chunk 0 (swapped operands: H^T, m in lane, h in regs) ----
        #pragma unroll
        for (int r = 0; r < 16; ++r) { h0[r] = 0.0f; h1[r] = 0.0f; }
        __builtin_amdgcn_s_setprio(1);
        #pragma unroll
        for (int ks = 0; ks < 8; ++ks) {
            const int off = (ks * 16 + hi * 8) ^ sw;
            bf16x8 a0 = *(const bf16x8*)&x0[off];
            bf16x8 a1 = *(const bf16x8*)&x1[off];
            bf16x8 wfr = __builtin_bit_cast(bf16x8, wf1r[ks]);
            h0 = __builtin_amdgcn_mfma_f32_32x32x16_bf16(wfr, a0, h0, 0, 0, 0);
            h1 = __builtin_amdgcn_mfma_f32_32x32x16_bf16(wfr, a1, h1, 0, 0, 0);
        }
        __builtin_amdgcn_s_setprio(0);
        unsigned short* hw0 = &Hs[0][l32 * 128];
        unsigned short* hw1 = &Hs[0][(32 + l32) * 128];
        #pragma unroll
        for (int q = 0; q < 4; ++q) {
            const int cb = (w * 32 + 8 * q + 4 * hi) ^ sw;
            float f0 = fmaxf(h0[4 * q + 0] + bqr[q].x, 0.0f);
            float f1 = fmaxf(h0[4 * q + 1] + bqr[q].y, 0.0f);
            float f2 = fmaxf(h0[4 * q + 2] + bqr[q].z, 0.0f);
            float f3 = fmaxf(h0[4 * q + 3] + bqr[q].w, 0.0f);
            bf16x4 v = { (__bf16)f0, (__bf16)f1, (__bf16)f2, (__bf16)f3 };
            *(bf16x4*)&hw0[cb] = v;
            f0 = fmaxf(h1[4 * q + 0] + bqr[q].x, 0.0f);
            f1 = fmaxf(h1[4 * q + 1] + bqr[q].y, 0.0f);
            f2 = fmaxf(h1[4 * q + 2] + bqr[q].z, 0.0f);
            f3 = fmaxf(h1[4 * q + 3] + bqr[q].w, 0.0f);
            bf16x4 v2 = { (__bf16)f0, (__bf16)f1, (__bf16)f2, (__bf16)f3 };
            *(bf16x4*)&hw1[cb] = v2;
        }
        asm volatile("s_waitcnt lgkmcnt(0)" ::: "memory");
        __builtin_amdgcn_sched_barrier(0);
        __builtin_amdgcn_s_barrier();                        // vmcnt NOT drained (wf2(0) in flight)
    }

    // ---- main loop: one barrier per chunk; counted vmcnt, never 0 until the last chunk ----
    for (int c = 0; c < 8; ++c) {
        const unsigned short* hr0 = &Hs[c & 1][l32 * 128];
        const unsigned short* hr1 = &Hs[c & 1][(32 + l32) * 128];

        if (c < 7) {
            // issue wf1(c+1)+bias(c+1): 12 loads; their latency hides under phase B
            const unsigned short* w1p = W1F + ((size_t)((c + 1) * 4 + w) * 8) * 512 + lane * 8;
            #pragma unroll
            for (int ks = 0; ks < 8; ++ks) GLD(wf1r[ks], (const void*)(w1p + ks * 512));
            #pragma unroll
            for (int q = 0; q < 4; ++q) GLD(bqr[q], (const void*)&b1[(c + 1) * 128 + w * 32 + 8 * q + 4 * hi]);
            // outstanding: wf2(c)=16 (oldest) + 12 just issued -> wait to 12: wf2(c) ready
            VMWAIT(12);
        } else {
            VMWAIT(0);
        }

        // ---- phase B, chunk c ----
        __builtin_amdgcn_s_setprio(1);
        #pragma unroll
        for (int ks = 0; ks < 8; ++ks) {
            const int off = (ks * 16 + hi * 8) ^ sw;
            bf16x8 a0 = *(const bf16x8*)&hr0[off];
            bf16x8 a1 = *(const bf16x8*)&hr1[off];
            bf16x8 b0 = __builtin_bit_cast(bf16x8, wf2r[ks]);
            bf16x8 b1f = __builtin_bit_cast(bf16x8, wf2r[8 + ks]);
            acc[0][0] = __builtin_amdgcn_mfma_f32_32x32x16_bf16(a0, b0, acc[0][0], 0, 0, 0);
            acc[0][1] = __builtin_amdgcn_mfma_f32_32x32x16_bf16(a0, b1f, acc[0][1], 0, 0, 0);
            acc[1][0] = __builtin_amdgcn_mfma_f32_32x32x16_bf16(a1, b0, acc[1][0], 0, 0, 0);
            acc[1][1] = __builtin_amdgcn_mfma_f32_32x32x16_bf16(a1, b1f, acc[1][1], 0, 0, 0);
        }
        __builtin_amdgcn_s_setprio(0);

        if (c < 7) {
            // issue wf2(c+1): stays in flight across phase A + the barrier
            const unsigned short* w2p0 = W2F + ((size_t)(2 * w + 0) * 64 + (c + 1) * 8) * 512 + lane * 8;
            const unsigned short* w2p1 = W2F + ((size_t)(2 * w + 1) * 64 + (c + 1) * 8) * 512 + lane * 8;
            #pragma unroll
            for (int ks = 0; ks < 8; ++ks) {
                GLD(wf2r[ks],     (const void*)(w2p0 + ks * 512));
                GLD(wf2r[8 + ks], (const void*)(w2p1 + ks * 512));
            }
            // outstanding: wf1(c+1)+bias=12 (oldest) + wf2(c+1)=16 -> wait to 16: wf1 ready
            VMWAIT(16);

            // ---- phase A, chunk c+1 ----
            #pragma unroll
            for (int r = 0; r < 16; ++r) { h0[r] = 0.0f; h1[r] = 0.0f; }
            __builtin_amdgcn_s_setprio(1);
            #pragma unroll
            for (int ks = 0; ks < 8; ++ks) {
                const int off = (ks * 16 + hi * 8) ^ sw;
                bf16x8 a0 = *(const bf16x8*)&x0[off];
                bf16x8 a1 = *(const bf16x8*)&x1[off];
                bf16x8 wfr = __builtin_bit_cast(bf16x8, wf1r[ks]);
                h0 = __builtin_amdgcn_mfma_f32_32x32x16_bf16(wfr, a0, h0, 0, 0, 0);
                h1 = __builtin_amdgcn_mfma_f32_32x32x16_bf16(wfr, a1, h1, 0, 0, 0);
            }
            __builtin_amdgcn_s_setprio(0);

            // ---- write H(c+1) -> Hs[(c+1)&1] (anti-dep ordered by previous barrier) ----
            unsigned short* hw0 = &Hs[(c + 1) & 1][l32 * 128];
            unsigned short* hw1 = &Hs[(c + 1) & 1][(32 + l32) * 128];
            #pragma unroll
            for (int q = 0; q < 4; ++q) {
                const int cb = (w * 32 + 8 * q + 4 * hi) ^ sw;
                float f0 = fmaxf(h0[4 * q + 0] + bqr[q].x, 0.0f);
                float f1 = fmaxf(h0[4 * q + 1] + bqr[q].y, 0.0f);
                float f2 = fmaxf(h0[4 * q + 2] + bqr[q].z, 0.0f);
                float f3 = fmaxf(h0[4 * q + 3] + bqr[q].w, 0.0f);
                bf16x4 v = { (__bf16)f0, (__bf16)f1, (__bf16)f2, (__bf16)f3 };
                *(bf16x4*)&hw0[cb] = v;
                f0 = fmaxf(h1[4 * q + 0] + bqr[q].x, 0.0f);
                f1 = fmaxf(h1[4 * q + 1] + bqr[q].y, 0.0f);
                f2 = fmaxf(h1[4 * q + 2] + bqr[q].z, 0.0f);
                f3 = fmaxf(h1[4 * q + 3] + bqr[q].w, 0.0f);
                bf16x4 v2 = { (__bf16)f0, (__bf16)f1, (__bf16)f2, (__bf16)f3 };
                *(bf16x4*)&hw1[cb] = v2;
            }

            asm volatile("s_waitcnt lgkmcnt(0)" ::: "memory");   // my ds reads+writes retired
            __builtin_amdgcn_sched_barrier(0);
            __builtin_amdgcn_s_barrier();                        // vmcnt NOT drained
        }
    }

    // ---- epilogue: + b2, store f32 ----
    #pragma unroll
    for (int ni = 0; ni < 2; ++ni) {
        const int col = (2 * w + ni) * 32 + l32;
        const float bb = b2[col];
        #pragma unroll
        for (int mi = 0; mi < 2; ++mi) {
            #pragma unroll
            for (int r = 0; r < 16; ++r) {
                const long row = r0 + mi * 32 + (r & 3) + 8 * (r >> 2) + 4 * hi;
                out[row * 256 + col] = acc[mi][ni][r] + bb;
            }
        }
    }
}

extern "C" void kernel_launch(void* const* d_in, const int* in_sizes, int n_in,
                              void* d_out, int out_size, void* d_ws, size_t ws_size,
                              hipStream_t stream) {
    (void)in_sizes; (void)n_in; (void)out_size; (void)ws_size;
    const float* hole  = (const float*)d_in[0];
    const float* board = (const float*)d_in[1];
    const float* W1    = (const float*)d_in[2];
    const float* b1    = (const float*)d_in[3];
    const float* W2    = (const float*)d_in[4];
    const float* b2    = (const float*)d_in[5];
    float* out = (float*)d_out;

    unsigned short* W1F = (unsigned short*)d_ws;            // 131072 bf16 = 256 KB
    unsigned short* W2F = W1F + 131072;                     // 262144 bf16 = 512 KB

    conv_w<<<1536, 256, 0, stream>>>(W1, W2, W1F, W2F);
    mlp_fused<<<131072 / 64, 256, 0, stream>>>(hole, board, b1, b2, W1F, W2F, out);
}

// Round 5
// 293.752 us; speedup vs baseline: 1.1273x; 1.1273x over previous
//
#include <hip/hip_runtime.h>

typedef __bf16 bf16x8 __attribute__((ext_vector_type(8)));
typedef float f32x16 __attribute__((ext_vector_type(16)));

__device__ __forceinline__ unsigned short f2bf(float f) {
    union { float f; unsigned u; } v; v.f = f;
    unsigned r = (v.u + 0x7FFFu + ((v.u >> 16) & 1u)) >> 16;
    return (unsigned short)r;
}
// pack two f32 -> one u32 of 2x bf16 (RNE; compiler fuses to v_cvt_pk_bf16_f32)
__device__ __forceinline__ unsigned pk2(float lo, float hi) {
    union { unsigned u; __bf16 h[2]; } t;
    t.h[0] = (__bf16)lo; t.h[1] = (__bf16)hi; return t.u;
}

// ---- weight conversion into MFMA fragment order (32x32x16 bf16) ----
// Frag mapping: lane l holds W[k0 + (l>>5)*8 + j][n0 + (l&31)], j=0..7.
// W1F index = ((g*8 + kb)*64 + l)*8 + j   (g: hidden col-group 0..31, kb: K-step 0..7, K pad 119->128)
// W2F index = ((gn*64 + kb)*64 + l)*8 + j (gn: out col-group 0..7, kb: K-step 0..63)
__global__ void conv_w(const float* __restrict__ W1, const float* __restrict__ W2,
                       unsigned short* __restrict__ W1F, unsigned short* __restrict__ W2F) {
    int b = blockIdx.x;
    if (b < 512) {
        int idx = b * 256 + threadIdx.x;                   // 131072
        int j = idx & 7, l = (idx >> 3) & 63, kb = (idx >> 9) & 7, g = idx >> 12;
        int k = kb * 16 + (l >> 5) * 8 + j;
        int h = g * 32 + (l & 31);
        float v = (k < 119) ? W1[(size_t)k * 1024 + h] : 0.0f;
        W1F[idx] = f2bf(v);
    } else {
        int idx = (b - 512) * 256 + threadIdx.x;           // 262144
        int j = idx & 7, l = (idx >> 3) & 63, kb = (idx >> 9) & 63, gn = idx >> 15;
        int k = kb * 16 + (l >> 5) * 8 + j;
        int n = gn * 32 + (l & 31);
        W2F[idx] = f2bf(W2[(size_t)k * 256 + n]);
    }
}

// ---- fused features + MLP ----
// 256 threads (4 waves), 64 rows/block, grid 2048. chunk = 128 hidden cols (8 chunks).
// ALL main-loop LDS traffic is FRAGMENT-ORDERED (addr = base + lane*16): zero bank conflicts.
//   Phase A (swapped): h_acc = mfma(W1frag, Xfrag) -> H^T (m in lane, h in regs).
//   pack to bf16 + __shfl_xor(32) exchange converts h_acc directly into the phase-B
//   A-fragment layout (lane l: H[m=l&31][h=kc*16+(l>>5)*8+j]) -> 4x ds_write_b128, lane-linear.
//   Phase B reads 16 lane-linear ds_read_b128 + W2 frags, accumulates OUT[m][n].
// Chunk rotation per block decorrelates weight-line demand and block phases.
// Compiler-scheduled loads (R4 proved rigid pinning loses); one barrier per chunk.
__global__ __launch_bounds__(256, 3) void mlp_fused(
    const float* __restrict__ hole, const float* __restrict__ board,
    const float* __restrict__ b1, const float* __restrict__ b2,
    const unsigned short* __restrict__ W1F, const unsigned short* __restrict__ W2F,
    float* __restrict__ out)
{
    __shared__ unsigned short Xsf[16 * 512];   // 16KB frag-ordered X: ((mi*8+ks)*64+lane)*8
    __shared__ unsigned short HsF[32 * 512];   // 32KB frag-ordered H, dbuf: ((par*16+mi*8+kc)*64+lane)*8
    // rowmajX (64 rows x 128 shorts) aliases HsF[0..8191] during init only

    const int tid  = threadIdx.x;
    const int w    = tid >> 6;
    const int lane = tid & 63;
    const int l32  = lane & 31;
    const int hi   = lane >> 5;      // 0/1 half-wave
    const long r0  = (long)blockIdx.x * 64;
    const int crot = (int)((blockIdx.x + (blockIdx.x >> 8)) & 7);

    // ---------------- feature extraction: thread t < 64 handles row r0+t ----------------
    if (tid < 64) {
        const long r = r0 + tid;
        const float4* hp = (const float4*)(hole + r * 52);
        const float4* bp = (const float4*)(board + r * 52);
        unsigned long long hm = 0ull, bm = 0ull;
        #pragma unroll
        for (int i = 0; i < 13; ++i) {
            float4 h4 = hp[i], b4 = bp[i];
            int base = i * 4;
            hm |= ((unsigned long long)(h4.x > 0.5f)) << (base + 0);
            hm |= ((unsigned long long)(h4.y > 0.5f)) << (base + 1);
            hm |= ((unsigned long long)(h4.z > 0.5f)) << (base + 2);
            hm |= ((unsigned long long)(h4.w > 0.5f)) << (base + 3);
            bm |= ((unsigned long long)(b4.x > 0.5f)) << (base + 0);
            bm |= ((unsigned long long)(b4.y > 0.5f)) << (base + 1);
            bm |= ((unsigned long long)(b4.z > 0.5f)) << (base + 2);
            bm |= ((unsigned long long)(b4.w > 0.5f)) << (base + 3);
        }
        const unsigned long long am = hm | bm;
        const int bcount = __popcll(bm);
        const int hcount = __popcll(hm);

        int pairs_b = 0, pairs_a = 0;
        bool trips_b = false, trips_a = false;
        unsigned prb = 0, pra = 0;
        #pragma unroll
        for (int rr = 0; rr < 13; ++rr) {
            int cb = __popc((unsigned)((bm >> (4 * rr)) & 0xFull));
            int ca = __popc((unsigned)((am >> (4 * rr)) & 0xFull));
            pairs_b += (cb >= 2); trips_b = trips_b || (cb >= 3); prb |= (unsigned)(cb > 0) << rr;
            pairs_a += (ca >= 2); trips_a = trips_a || (ca >= 3); pra |= (unsigned)(ca > 0) << rr;
        }
        const unsigned long long SM = 0x1111111111111ull;
        int bscm = 0, ascm = 0;
        #pragma unroll
        for (int s = 0; s < 4; ++s) {
            int bs = __popcll(bm & (SM << s));
            int as = __popcll(am & (SM << s));
            bscm = bs > bscm ? bs : bscm;
            ascm = as > ascm ? as : ascm;
        }
        float strength = trips_b ? 0.8f : (pairs_b >= 2 ? 0.6f : (pairs_b >= 1 ? 0.4f : 0.2f));
        if (bcount == 0) strength = 0.0f;
        float flush_b = (bscm >= 3 && bcount > 0) ? 1.0f : 0.0f;
        bool sb = false;
        #pragma unroll
        for (int i = 0; i < 13; ++i) sb = sb || (__popc((prb >> i) & 0x1Fu) >= 3);
        float straight_b = (sb && bcount > 0) ? 1.0f : 0.0f;
        float gr0 = (bcount == 0) ? 1.0f : 0.0f;
        float gr3 = (bcount == 3) ? 1.0f : 0.0f;
        float gr4 = (bcount == 4) ? 1.0f : 0.0f;
        float gr5 = (bcount == 5) ? 1.0f : 0.0f;
        float valid = (hcount >= 2 && bcount >= 1) ? 1.0f : 0.0f;
        float flush_draw = (ascm == 4) ? 1.0f : 0.0f;
        float flush_outs = fmaxf(0.0f, 13.0f - (float)ascm) * (1.0f / 13.0f);
        int first = -1;
        #pragma unroll
        for (int i = 0; i < 13; ++i) {
            bool qq = (((pra >> i) & 1u) != 0u) && (__popc((pra >> i) & 0x1Fu) >= 4);
            if (qq && first < 0) first = i;
        }
        float straight_draw = (first >= 0) ? 1.0f : 0.0f;
        float straight_outs = 0.0f;
        if (first >= 0) {
            int c4 = __popc((pra >> first) & 0xFu);
            straight_outs = (c4 >= 4) ? 0.4f : 0.2f;
        }
        float total_outs = flush_draw * flush_outs * 9.0f + straight_draw * straight_outs * 8.0f;
        float remaining = 52.0f - (float)(hcount + bcount);
        float equity = 0.0f;
        if (remaining > 0.0f) equity = fminf(1.0f, total_outs / fmaxf(remaining, 1.0f));
        float hit_pair  = (pairs_a >= 1) ? 1.0f : 0.0f;
        float hit_trips = trips_a ? 1.0f : 0.0f;
        float hit_two   = (pairs_a >= 2) ? 1.0f : 0.0f;

        unsigned short* xrow = &HsF[tid * 128];    // row-major X temp (aliases HsF par0)
        #pragma unroll
        for (int i = 0; i < 52; ++i) xrow[i]      = ((hm >> i) & 1ull) ? (unsigned short)0x3F80 : (unsigned short)0;
        #pragma unroll
        for (int i = 0; i < 52; ++i) xrow[52 + i] = ((bm >> i) & 1ull) ? (unsigned short)0x3F80 : (unsigned short)0;
        float feats[15] = { strength, flush_b, straight_b, gr0, gr3, gr4, gr5,
                            valid * flush_draw, valid * flush_outs, valid * straight_draw,
                            valid * straight_outs, valid * equity,
                            valid * hit_pair, valid * hit_trips, valid * hit_two };
        #pragma unroll
        for (int i = 0; i < 15; ++i) xrow[104 + i] = f2bf(feats[i]);
        #pragma unroll
        for (int i = 119; i < 128; ++i) xrow[i] = 0;
    }

    f32x16 acc[2][2];
    #pragma unroll
    for (int a = 0; a < 2; ++a)
        #pragma unroll
        for (int b = 0; b < 2; ++b)
            #pragma unroll
            for (int r = 0; r < 16; ++r) acc[a][b][r] = 0.0f;

    __syncthreads();   // rowmajX visible

    // ---- one-time conversion: row-major X -> frag-ordered Xsf (wave w builds ks={2w,2w+1}) ----
    bf16x8 cf[2][2];
    #pragma unroll
    for (int mi = 0; mi < 2; ++mi)
        #pragma unroll
        for (int jj = 0; jj < 2; ++jj) {
            const int ks = 2 * w + jj;
            cf[mi][jj] = *(const bf16x8*)&HsF[(mi * 32 + l32) * 128 + ks * 16 + hi * 8];
        }
    __syncthreads();   // all conversion reads of rowmajX done (HsF free for H)
    #pragma unroll
    for (int mi = 0; mi < 2; ++mi)
        #pragma unroll
        for (int jj = 0; jj < 2; ++jj)
            *(bf16x8*)&Xsf[((mi * 8 + 2 * w + jj) * 64 + lane) * 8] = cf[mi][jj];
    __syncthreads();   // Xsf visible

    f32x16 h0, h1;

    // pack h_acc (H^T: m in lane, h in regs) + bias/relu, then lane^32 exchange ->
    // phase-B A-frag pair (kc 2w+0 / 2w+1): lane l holds H[m=l&31][h=kc*16+(l>>5)*8+j]
    auto packswap = [&](const f32x16& h, const float4* bq, uint4& f0, uint4& f1) {
        float v[16];
        #pragma unroll
        for (int q = 0; q < 4; ++q) {
            v[4 * q + 0] = fmaxf(h[4 * q + 0] + bq[q].x, 0.0f);
            v[4 * q + 1] = fmaxf(h[4 * q + 1] + bq[q].y, 0.0f);
            v[4 * q + 2] = fmaxf(h[4 * q + 2] + bq[q].z, 0.0f);
            v[4 * q + 3] = fmaxf(h[4 * q + 3] + bq[q].w, 0.0f);
        }
        unsigned p0 = pk2(v[0], v[1]),  p1 = pk2(v[2], v[3]);
        unsigned p2 = pk2(v[4], v[5]),  p3 = pk2(v[6], v[7]);
        unsigned p4 = pk2(v[8], v[9]),  p5 = pk2(v[10], v[11]);
        unsigned p6 = pk2(v[12], v[13]), p7 = pk2(v[14], v[15]);
        unsigned q0 = (unsigned)__shfl_xor((int)p0, 32, 64);
        unsigned q1 = (unsigned)__shfl_xor((int)p1, 32, 64);
        unsigned q2 = (unsigned)__shfl_xor((int)p2, 32, 64);
        unsigned q3 = (unsigned)__shfl_xor((int)p3, 32, 64);
        unsigned q4 = (unsigned)__shfl_xor((int)p4, 32, 64);
        unsigned q5 = (unsigned)__shfl_xor((int)p5, 32, 64);
        unsigned q6 = (unsigned)__shfl_xor((int)p6, 32, 64);
        unsigned q7 = (unsigned)__shfl_xor((int)p7, 32, 64);
        f0.x = hi ? q2 : p0;  f0.y = hi ? q3 : p1;  f0.z = hi ? p2 : q0;  f0.w = hi ? p3 : q1;
        f1.x = hi ? q6 : p4;  f1.y = hi ? q7 : p5;  f1.z = hi ? p6 : q4;  f1.w = hi ? p7 : q5;
    };

    // ---- prologue: phase A chunk crot -> HsF[par=0] ----
    {
        const int cc = crot;
        const unsigned short* w1p = W1F + ((size_t)(cc * 4 + w) * 8) * 512 + lane * 8;
        float4 bq[4];
        #pragma unroll
        for (int q = 0; q < 4; ++q) bq[q] = *(const float4*)&b1[cc * 128 + w * 32 + 8 * q + 4 * hi];
        #pragma unroll
        for (int r = 0; r < 16; ++r) { h0[r] = 0.0f; h1[r] = 0.0f; }
        #pragma unroll
        for (int ks = 0; ks < 8; ++ks) {
            bf16x8 wfr = *(const bf16x8*)(w1p + ks * 512);
            bf16x8 x0 = *(const bf16x8*)&Xsf[((0 * 8 + ks) * 64 + lane) * 8];
            bf16x8 x1 = *(const bf16x8*)&Xsf[((1 * 8 + ks) * 64 + lane) * 8];
            h0 = __builtin_amdgcn_mfma_f32_32x32x16_bf16(wfr, x0, h0, 0, 0, 0);
            h1 = __builtin_amdgcn_mfma_f32_32x32x16_bf16(wfr, x1, h1, 0, 0, 0);
        }
        uint4 f00, f01, f10, f11;
        packswap(h0, bq, f00, f01);
        packswap(h1, bq, f10, f11);
        unsigned short* hw = &HsF[0];
        *(uint4*)&hw[((0 * 8 + 2 * w + 0) * 64 + lane) * 8] = f00;
        *(uint4*)&hw[((0 * 8 + 2 * w + 1) * 64 + lane) * 8] = f01;
        *(uint4*)&hw[((1 * 8 + 2 * w + 0) * 64 + lane) * 8] = f10;
        *(uint4*)&hw[((1 * 8 + 2 * w + 1) * 64 + lane) * 8] = f11;
        asm volatile("s_waitcnt lgkmcnt(0)" ::: "memory");
        __builtin_amdgcn_s_barrier();
        __builtin_amdgcn_sched_barrier(0);
    }

    // ---- main loop: one barrier per chunk; all LDS lane-linear ----
    for (int i = 0; i < 8; ++i) {
        const int par = i & 1;
        const int cc  = (crot + i) & 7;

        // phase B, chunk cc
        {
            const unsigned short* hbase = &HsF[(size_t)par * 8192];
            const unsigned short* w2p0 = W2F + ((size_t)(2 * w + 0) * 64 + cc * 8) * 512 + lane * 8;
            const unsigned short* w2p1 = W2F + ((size_t)(2 * w + 1) * 64 + cc * 8) * 512 + lane * 8;
            #pragma unroll
            for (int kc = 0; kc < 8; ++kc) {
                bf16x8 a0  = *(const bf16x8*)&hbase[((0 * 8 + kc) * 64 + lane) * 8];
                bf16x8 a1  = *(const bf16x8*)&hbase[((1 * 8 + kc) * 64 + lane) * 8];
                bf16x8 b0  = *(const bf16x8*)(w2p0 + kc * 512);
                bf16x8 b1f = *(const bf16x8*)(w2p1 + kc * 512);
                acc[0][0] = __builtin_amdgcn_mfma_f32_32x32x16_bf16(a0, b0,  acc[0][0], 0, 0, 0);
                acc[0][1] = __builtin_amdgcn_mfma_f32_32x32x16_bf16(a0, b1f, acc[0][1], 0, 0, 0);
                acc[1][0] = __builtin_amdgcn_mfma_f32_32x32x16_bf16(a1, b0,  acc[1][0], 0, 0, 0);
                acc[1][1] = __builtin_amdgcn_mfma_f32_32x32x16_bf16(a1, b1f, acc[1][1], 0, 0, 0);
            }
        }

        if (i < 7) {
            const int cn = (crot + i + 1) & 7;
            // phase A, chunk cn
            const unsigned short* w1p = W1F + ((size_t)(cn * 4 + w) * 8) * 512 + lane * 8;
            float4 bq[4];
            #pragma unroll
            for (int q = 0; q < 4; ++q) bq[q] = *(const float4*)&b1[cn * 128 + w * 32 + 8 * q + 4 * hi];
            #pragma unroll
            for (int r = 0; r < 16; ++r) { h0[r] = 0.0f; h1[r] = 0.0f; }
            #pragma unroll
            for (int ks = 0; ks < 8; ++ks) {
                bf16x8 wfr = *(const bf16x8*)(w1p + ks * 512);
                bf16x8 x0 = *(const bf16x8*)&Xsf[((0 * 8 + ks) * 64 + lane) * 8];
                bf16x8 x1 = *(const bf16x8*)&Xsf[((1 * 8 + ks) * 64 + lane) * 8];
                h0 = __builtin_amdgcn_mfma_f32_32x32x16_bf16(wfr, x0, h0, 0, 0, 0);
                h1 = __builtin_amdgcn_mfma_f32_32x32x16_bf16(wfr, x1, h1, 0, 0, 0);
            }
            uint4 f00, f01, f10, f11;
            packswap(h0, bq, f00, f01);
            packswap(h1, bq, f10, f11);
            // write H(cn) -> HsF[par^1]; anti-dep vs other waves' reads of this buffer
            // (iteration i-1) is ordered by the previous barrier.
            unsigned short* hw = &HsF[(size_t)(par ^ 1) * 8192];
            *(uint4*)&hw[((0 * 8 + 2 * w + 0) * 64 + lane) * 8] = f00;
            *(uint4*)&hw[((0 * 8 + 2 * w + 1) * 64 + lane) * 8] = f01;
            *(uint4*)&hw[((1 * 8 + 2 * w + 0) * 64 + lane) * 8] = f10;
            *(uint4*)&hw[((1 * 8 + 2 * w + 1) * 64 + lane) * 8] = f11;

            asm volatile("s_waitcnt lgkmcnt(0)" ::: "memory");   // my ds reads+writes retired
            __builtin_amdgcn_s_barrier();
            __builtin_amdgcn_sched_barrier(0);
        }
    }

    // ---- epilogue: + b2, store f32 ----
    #pragma unroll
    for (int ni = 0; ni < 2; ++ni) {
        const int col = (2 * w + ni) * 32 + l32;
        const float bb = b2[col];
        #pragma unroll
        for (int mi = 0; mi < 2; ++mi) {
            #pragma unroll
            for (int r = 0; r < 16; ++r) {
                const long row = r0 + mi * 32 + (r & 3) + 8 * (r >> 2) + 4 * hi;
                out[row * 256 + col] = acc[mi][ni][r] + bb;
            }
        }
    }
}

extern "C" void kernel_launch(void* const* d_in, const int* in_sizes, int n_in,
                              void* d_out, int out_size, void* d_ws, size_t ws_size,
                              hipStream_t stream) {
    (void)in_sizes; (void)n_in; (void)out_size; (void)ws_size;
    const float* hole  = (const float*)d_in[0];
    const float* board = (const float*)d_in[1];
    const float* W1    = (const float*)d_in[2];
    const float* b1    = (const float*)d_in[3];
    const float* W2    = (const float*)d_in[4];
    const float* b2    = (const float*)d_in[5];
    float* out = (float*)d_out;

    unsigned short* W1F = (unsigned short*)d_ws;            // 131072 bf16 = 256 KB
    unsigned short* W2F = W1F + 131072;                     // 262144 bf16 = 512 KB

    conv_w<<<1536, 256, 0, stream>>>(W1, W2, W1F, W2F);
    mlp_fused<<<131072 / 64, 256, 0, stream>>>(hole, board, b1, b2, W1F, W2F, out);
}